// Round 11
// baseline (216.944 us; speedup 1.0000x reference)
//
#include <hip/hip_runtime.h>
#include <hip/hip_bf16.h>
#include <stdint.h>

// NearestUpsampling (x2) + 3x3 VALID conv == per-parity 2x2 conv on original x
// == implicit GEMM M=16*63*63=63504, N=(4 par)*(128 Cout), K=128c*4taps=512.
// R14 (resubmit; prior round was an infra failure, kernel audited clean):
//   R13 + vectorized chunked staging (G13 / Common-mistake #2, the last
//   untried textbook lever). R13 staged x via 64 SCALAR 4B global loads per
//   thread (2x request amplification from the q/q+1 overlap, low in-flight
//   bytes under the 64-VGPR budget). Now: 8 chunks of 16 channels; per chunk
//   each thread does ONE global_load_lds dwordx4 into a linear Xs buffer
//   (dest == base + t*16, exactly the gll wave-uniform+lane*16 pattern),
//   double-buffered, 1 barrier/chunk; a build pass assembles the 4 taps from
//   Xs (conflict-free LDS reads) into the SAME verified As layout (b128,
//   R11 bank-minimal). x request bytes halve (exact 64KB/block), global
//   instrs 64 -> 8 per thread. K-loop + epilogue = R13 verbatim.
//   As shrinks to 63 rows: total LDS 65520+16384 = 81904 B = exactly 2
//   blocks/CU. (af row-63 reads hit Xs garbage; q=63 column is discarded.)

#define B_    16
#define CIN   128
#define HIN   64
#define WIN   64
#define COUT  128
#define HO    126
#define WO    126
#define KTILES 16
#define AS_K  520              // bf16 row stride: 1040 B (16B-aligned)
#define AS_ROWS 63
#define AS_BYTES (AS_ROWS * AS_K * 2)   // 65520
#define XS_BUF_F 2048          // floats per Xs buffer: 16c*2r*64w

typedef __bf16 bf16;
typedef __bf16 bf16x8 __attribute__((ext_vector_type(8)));
typedef float  floatx4 __attribute__((ext_vector_type(4)));
typedef float  floatx2 __attribute__((ext_vector_type(2)));

// ---------------------------------------------------------------------------
// Prep: combine 3x3 weights into parity 2x2 weights (bf16).
// Layout: wb[(((kt*4 + par)*128 + o)*32 + k32)], k = kt*32+k32 = c*4 + u*2 + v.
// ---------------------------------------------------------------------------
__global__ void prep_weights(const float* __restrict__ w, bf16* __restrict__ wb) {
    int idx = blockIdx.x * 256 + threadIdx.x;
    if (idx >= 4 * KTILES * COUT * 32) return;   // 262144
    int k32 = idx & 31;
    int o   = (idx >> 5) & 127;
    int par = (idx >> 12) & 3;
    int kt  = idx >> 14;
    int k = kt * 32 + k32;
    int c = k >> 2, u = (k >> 1) & 1, v = k & 1;
    int a = par >> 1, bp = par & 1;
    int dy0, dy1, ndy, dx0, dx1, ndx;
    if (u == 0) { if (a == 0) { dy0 = 0; dy1 = 1; ndy = 2; } else { dy0 = 0; dy1 = 0; ndy = 1; } }
    else        { if (a == 0) { dy0 = 2; dy1 = 2; ndy = 1; } else { dy0 = 1; dy1 = 2; ndy = 2; } }
    if (v == 0) { if (bp == 0) { dx0 = 0; dx1 = 1; ndx = 2; } else { dx0 = 0; dx1 = 0; ndx = 1; } }
    else        { if (bp == 0) { dx0 = 2; dx1 = 2; ndx = 1; } else { dx0 = 1; dx1 = 2; ndx = 2; } }
    const float* wp = w + (o * CIN + c) * 9;
    float s = wp[dy0 * 3 + dx0];
    if (ndx == 2) s += wp[dy0 * 3 + dx1];
    if (ndy == 2) { s += wp[dy1 * 3 + dx0]; if (ndx == 2) s += wp[dy1 * 3 + dx1]; }
    wb[idx] = (bf16)s;
}

// ---------------------------------------------------------------------------
// Main kernel. 512 threads = 8 waves: a = wid>>2 (row parity), oq = wid&3
// (o-quarter). Wave: 32 o x 63 m x both bp via mfma(wf, af) -> D[row=o][col=m].
// One block == one (b,p) input row: q = lane, y = 2p+a.
// ---------------------------------------------------------------------------
__global__ __launch_bounds__(512, 4)
void upconv_gemm(const float* __restrict__ x, const bf16* __restrict__ wb,
                 const float* __restrict__ bias, float* __restrict__ out) {
    __shared__ __align__(16) char smem[AS_BYTES + 2 * XS_BUF_F * 4];  // 81904 B
    bf16*  As  = (bf16*)smem;
    float* Xs  = (float*)(smem + AS_BYTES);        // [2][16][2][64] f32
    floatx2* Ld2 = (floatx2*)smem;                 // epilogue overlay [128][65] f2

    const int t    = threadIdx.x;
    const int lane = t & 63;
    const int wid  = t >> 6;
    const int a    = wid >> 2;          // output-row parity
    const int oq   = wid & 3;           // o-quarter
    const int quad = lane >> 4;
    const int l15  = lane & 15;
    const int kq   = quad * 8;

    const int bid = blockIdx.x;
    const int b   = bid / 63;           // batch
    const int p   = bid - b * 63;       // input row (0..62)

    // ---- vectorized chunked staging: 8 chunks x 16 channels ----
    // chunk-load: thread t -> one dwordx4: channel cl = t>>5, row r = (t>>4)&1,
    // w-seg = t&15. Xs dest offset = t*16 B (linear in t == gll pattern).
    const int cl = t >> 5;              // 0..15 chunk-local channel
    const int rl = (t >> 4) & 1;        // input row offset (p / p+1)
    const int w4 = t & 15;              // float4 segment
    const float* gsrc = x + ((b * CIN + cl) * HIN + (p + rl)) * WIN + w4 * 4;

    #define GLL_CHUNK(CH) \
        __builtin_amdgcn_global_load_lds( \
            (const __attribute__((address_space(1))) uint32_t*)(const void*)(gsrc + (CH) * 16 * HIN * WIN), \
            (__attribute__((address_space(3))) uint32_t*)(void*)(Xs + ((CH) & 1) * XS_BUF_F + t * 4), \
            16, 0, 0)

    GLL_CHUNK(0);

    #pragma unroll
    for (int ch = 0; ch < 8; ++ch) {
        __syncthreads();                 // chunk ch landed; prev builds done
        if (ch < 7) GLL_CHUNK(ch + 1);   // issue next chunk (flies under build)
        // build As rows from Xs[ch&1]: wave wid handles channels 2*wid, 2*wid+1
        if (lane < 63) {
            const float* Xb = Xs + (ch & 1) * XS_BUF_F + (2 * wid) * 128;
            const float a00 = Xb[lane],       a01 = Xb[lane + 1];
            const float a10 = Xb[64 + lane],  a11 = Xb[64 + lane + 1];
            const float b00 = Xb[128 + lane], b01 = Xb[128 + lane + 1];
            const float b10 = Xb[192 + lane], b11 = Xb[192 + lane + 1];
            bf16x8 v;
            v[0] = (bf16)a00; v[1] = (bf16)a01; v[2] = (bf16)a10; v[3] = (bf16)a11;
            v[4] = (bf16)b00; v[5] = (bf16)b01; v[6] = (bf16)b10; v[7] = (bf16)b11;
            *(bf16x8*)&As[lane * AS_K + (ch * 16 + 2 * wid) * 4] = v;
        }
    }
    __syncthreads();                     // last builds visible

    // --- K-loop (R13 verbatim): no barriers, wf straight from global ---
    const bf16* wwave = wb + ((a * 2) * COUT + oq * 32 + l15) * 32 + kq;

    floatx4 acc[2][4][2] = {};   // [bp][mt][nt]

    #pragma unroll
    for (int kt = 0; kt < KTILES; ++kt) {
        bf16x8 af[4], wf[2][2];
        #pragma unroll
        for (int i = 0; i < 4; ++i)
            af[i] = *(const bf16x8*)&As[(i * 16 + l15) * AS_K + kt * 32 + kq];
        #pragma unroll
        for (int bp = 0; bp < 2; ++bp)
            #pragma unroll
            for (int nt = 0; nt < 2; ++nt)
                wf[bp][nt] = *(const bf16x8*)(wwave
                    + (kt * 4 * COUT + bp * COUT + nt * 16) * 32);
        #pragma unroll
        for (int bp = 0; bp < 2; ++bp)
            #pragma unroll
            for (int mt = 0; mt < 4; ++mt)
                #pragma unroll
                for (int nt = 0; nt < 2; ++nt)
                    acc[bp][mt][nt] = __builtin_amdgcn_mfma_f32_16x16x32_bf16(
                        wf[bp][nt], af[mt], acc[bp][mt][nt], 0, 0, 0);
    }

    // ---- two-phase epilogue (R13 verbatim): phase ap = output-row parity ----
    float bv[2][4];
    #pragma unroll
    for (int nt = 0; nt < 2; ++nt)
        #pragma unroll
        for (int ri = 0; ri < 4; ++ri)
            bv[nt][ri] = bias[oq * 32 + nt * 16 + quad * 4 + ri];

    const int y0 = 2 * p;

    #pragma unroll
    for (int ap = 0; ap < 2; ++ap) {
        __syncthreads();   // ap=0: As K-loop reads done; ap=1: phase-0 reads done

        if (a == ap) {
            #pragma unroll
            for (int mt = 0; mt < 4; ++mt)
                #pragma unroll
                for (int nt = 0; nt < 2; ++nt)
                    #pragma unroll
                    for (int ri = 0; ri < 4; ++ri) {
                        const int o = oq * 32 + nt * 16 + quad * 4 + ri;
                        const int q = mt * 16 + l15;          // 63 unused, in-bounds
                        floatx2 r;
                        r[0] = acc[0][mt][nt][ri] + bv[nt][ri];
                        r[1] = acc[1][mt][nt][ri] + bv[nt][ri];
                        Ld2[o * 65 + q] = r;
                    }
        }
        __syncthreads();

        // streaming store: 128 whole output rows (one per o), 16 per wave.
        #pragma unroll
        for (int i = 0; i < 16; ++i) {
            const int o = wid * 16 + i;
            if (lane < 63) {
                floatx2 v = Ld2[o * 65 + lane];
                float* dst = out + ((b * COUT + o) * HO + (y0 + ap)) * WO + 2 * lane;
                __builtin_nontemporal_store(v, (floatx2*)dst);
            }
        }
    }
}

extern "C" void kernel_launch(void* const* d_in, const int* in_sizes, int n_in,
                              void* d_out, int out_size, void* d_ws, size_t ws_size,
                              hipStream_t stream) {
    const float* x    = (const float*)d_in[0];
    const float* w    = (const float*)d_in[1];
    const float* bias = (const float*)d_in[2];
    float* out = (float*)d_out;
    bf16* wb = (bf16*)d_ws;   // 512 KB

    prep_weights<<<(4 * KTILES * COUT * 32 + 255) / 256, 256, 0, stream>>>(w, wb);

    upconv_gemm<<<dim3(B_ * 63), 512, 0, stream>>>(x, wb, bias, out);   // 1008 blocks
}